// Round 1
// baseline (206.650 us; speedup 1.0000x reference)
//
#include <hip/hip_runtime.h>
#include <stdint.h>

#define N_ROWS 8192
#define FEAT   256

typedef __bf16 bf16x8 __attribute__((ext_vector_type(8)));
typedef float  f32x4  __attribute__((ext_vector_type(4)));

__device__ __forceinline__ unsigned short f2bf(float x) {
    union { float f; uint32_t u; } v; v.f = x;
    uint32_t u = v.u;
    // round-to-nearest-even bf16 (no NaN inputs here)
    return (unsigned short)((u + 0x7FFFu + ((u >> 16) & 1u)) >> 16);
}

// ---------------- Kernel 1: row L2-normalize, emit fp32 + bf16 copies ------
__global__ void knorm(const float* __restrict__ feat,
                      float* __restrict__ fout,
                      unsigned short* __restrict__ fb) {
    int wave = threadIdx.x >> 6;
    int lane = threadIdx.x & 63;
    int row  = blockIdx.x * 4 + wave;          // 4 waves/block, 1 row/wave
    const float4* src = (const float4*)(feat + row * FEAT);
    float4 v = src[lane];                       // 64 lanes x 4 = 256
    float ss = v.x*v.x + v.y*v.y + v.z*v.z + v.w*v.w;
    #pragma unroll
    for (int off = 1; off < 64; off <<= 1) ss += __shfl_xor(ss, off);
    float inv = 1.0f / fmaxf(sqrtf(ss), 1e-12f);
    float4 o; o.x = v.x*inv; o.y = v.y*inv; o.z = v.z*inv; o.w = v.w*inv;
    ((float4*)(fout + row * FEAT))[lane] = o;
    ushort4 b;
    b.x = f2bf(o.x); b.y = f2bf(o.y); b.z = f2bf(o.z); b.w = f2bf(o.w);
    ((ushort4*)(fb + row * FEAT))[lane] = b;
}

// ---------------- Kernel 2: tiled f@f^T with fused exp-sum ----------------
// grid (32, 8): blockIdx.x = row-block of 256 rows (8 waves x 32 rows),
//               blockIdx.y = column split of 1024 cols.
// Fixed-max logsumexp: s <= 1, so accumulate exp((s-1)/T) = exp2(s*K - K).
#define CT 64           // cols staged per chunk
#define LDS_STRIDE 264  // 256 + 8 pad: dword stride 132 % 32 = 4 -> 2-way max

__global__ __launch_bounds__(512)
void kmain(const unsigned short* __restrict__ fb, float* __restrict__ partial) {
    __shared__ unsigned short Bs[CT][LDS_STRIDE];   // 33,792 B
    const int t    = threadIdx.x;
    const int lane = t & 63;
    const int wave = t >> 6;          // 0..7
    const int quad = lane >> 4;       // 0..3
    const int l15  = lane & 15;
    const int rw    = blockIdx.x * 256 + wave * 32;   // this wave's 32 rows
    const int cbase = blockIdx.y * 1024;
    const float Kc = 20.60992915555662f;              // log2(e)/0.07

    // A fragments for 32 rows x K=256, resident in registers (64 VGPRs)
    bf16x8 af[2][8];
    #pragma unroll
    for (int rf = 0; rf < 2; ++rf)
        #pragma unroll
        for (int ks = 0; ks < 8; ++ks) {
            int row = rw + rf * 16 + l15;
            int k   = ks * 32 + quad * 8;
            af[rf][ks] = *(const bf16x8*)(fb + row * FEAT + k);
        }

    float lsum[2][4] = {{0.f,0.f,0.f,0.f},{0.f,0.f,0.f,0.f}};

    for (int ct = 0; ct < 1024 / CT; ++ct) {
        __syncthreads();
        const int c0 = cbase + ct * CT;
        // stage 64 cols x 256 k (32 KB) with 512 threads, 16B each x4
        #pragma unroll
        for (int i = 0; i < 4; ++i) {
            int idx = t + i * 512;
            int r = idx >> 5;
            int o = (idx & 31) * 8;
            *(uint4*)(&Bs[r][o]) = *(const uint4*)(fb + (c0 + r) * FEAT + o);
        }
        __syncthreads();

        #pragma unroll
        for (int g = 0; g < 4; ++g) {
            const int cg = c0 + g * 16;
            f32x4 acc0 = {0.f,0.f,0.f,0.f};
            f32x4 acc1 = {0.f,0.f,0.f,0.f};
            #pragma unroll
            for (int ks = 0; ks < 8; ++ks) {
                bf16x8 b = *(const bf16x8*)(&Bs[g * 16 + l15][ks * 32 + quad * 8]);
                acc0 = __builtin_amdgcn_mfma_f32_16x16x32_bf16(af[0][ks], b, acc0, 0, 0, 0);
                acc1 = __builtin_amdgcn_mfma_f32_16x16x32_bf16(af[1][ks], b, acc1, 0, 0, 0);
            }
            const bool dg = (cg < rw + 32) && (cg + 16 > rw);  // wave-uniform
            const int C = cg + l15;
            #pragma unroll
            for (int r = 0; r < 4; ++r) {
                float e0 = __builtin_amdgcn_exp2f(fmaf(acc0[r], Kc, -Kc));
                float e1 = __builtin_amdgcn_exp2f(fmaf(acc1[r], Kc, -Kc));
                if (dg) {
                    int R0 = rw + quad * 4 + r;     // rf = 0
                    if (R0 == C)      e0 = 0.f;     // mask j == i
                    if (R0 + 16 == C) e1 = 0.f;     // rf = 1
                }
                lsum[0][r] += e0;
                lsum[1][r] += e1;
            }
        }
    }

    // reduce across the 16 lanes (cols) sharing each row
    #pragma unroll
    for (int rf = 0; rf < 2; ++rf)
        #pragma unroll
        for (int r = 0; r < 4; ++r) {
            float v = lsum[rf][r];
            v += __shfl_xor(v, 1);
            v += __shfl_xor(v, 2);
            v += __shfl_xor(v, 4);
            v += __shfl_xor(v, 8);
            lsum[rf][r] = v;
        }
    if (l15 == 0) {
        #pragma unroll
        for (int rf = 0; rf < 2; ++rf)
            #pragma unroll
            for (int r = 0; r < 4; ++r) {
                int row = rw + rf * 16 + quad * 4 + r;
                partial[blockIdx.y * N_ROWS + row] = lsum[rf][r];
            }
    }
}

// ---------------- Kernel 3: positive dot (fp32) + combine + mean ----------
__global__ void kfin(const float* __restrict__ f,
                     const float* __restrict__ partial,
                     float* __restrict__ out) {
    int wave = threadIdx.x >> 6;
    int lane = threadIdx.x & 63;
    int row  = blockIdx.x * 4 + wave;
    const float4* a = (const float4*)(f + row * FEAT);
    const float4* b = (const float4*)(f + (row ^ 1) * FEAT);
    float4 av = a[lane], bv = b[lane];
    float d = av.x*bv.x + av.y*bv.y + av.z*bv.z + av.w*bv.w;
    #pragma unroll
    for (int off = 1; off < 64; off <<= 1) d += __shfl_xor(d, off);
    float L = (lane < 8) ? partial[lane * N_ROWS + row] : 0.f;
    L += __shfl_xor(L, 1);
    L += __shfl_xor(L, 2);
    L += __shfl_xor(L, 4);
    if (lane == 0) {
        const float invT = 14.285714285714286f;
        // loss_i = 1/T + ln(L) - pos/T ; ln(L) = ln2 * log2(L)
        float loss = invT * (1.0f - d)
                   + 0.6931471805599453f * __builtin_amdgcn_logf(L);
        atomicAdd(out, loss * (1.0f / 8192.0f));
    }
}

extern "C" void kernel_launch(void* const* d_in, const int* in_sizes, int n_in,
                              void* d_out, int out_size, void* d_ws, size_t ws_size,
                              hipStream_t stream) {
    const float* feat = (const float*)d_in[0];
    float* out = (float*)d_out;
    char* ws = (char*)d_ws;
    float*          f       = (float*)ws;                           // 8 MB fp32
    unsigned short* fb      = (unsigned short*)(ws + (8u << 20));   // 4 MB bf16
    float*          partial = (float*)(ws + (12u << 20));           // 256 KB

    hipMemsetAsync(d_out, 0, sizeof(float), stream);
    knorm<<<N_ROWS / 4, 256, 0, stream>>>(feat, f, fb);
    kmain<<<dim3(32, 8), 512, 0, stream>>>(fb, partial);
    kfin<<<N_ROWS / 4, 256, 0, stream>>>(f, partial, out);
}

// Round 2
// 104.468 us; speedup vs baseline: 1.9781x; 1.9781x over previous
//
#include <hip/hip_runtime.h>
#include <stdint.h>

#define N_ROWS 8192
#define FEAT   256
#define YSPLIT 16
#define CPB    (N_ROWS / YSPLIT)   // 512 cols per kmain block
#define CT     64                  // cols staged per chunk
#define LDS_STRIDE 264             // 256 + 8 pad shorts

typedef __bf16 bf16x8 __attribute__((ext_vector_type(8)));
typedef float  f32x4  __attribute__((ext_vector_type(4)));

__device__ __forceinline__ unsigned short f2bf(float x) {
    union { float f; uint32_t u; } v; v.f = x;
    uint32_t u = v.u;
    return (unsigned short)((u + 0x7FFFu + ((u >> 16) & 1u)) >> 16);
}

// ---- Kernel 1: normalize rows -> bf16 copy; fused positive-pair dot ------
// 4 waves/block = 4 consecutive rows; pair (i, i^1) is within the block.
__global__ void knorm(const float* __restrict__ feat,
                      unsigned short* __restrict__ fb,
                      float* __restrict__ pos) {
    __shared__ float ex[4][FEAT];
    int wave = threadIdx.x >> 6;
    int lane = threadIdx.x & 63;
    int row  = blockIdx.x * 4 + wave;
    float4 v = ((const float4*)(feat + row * FEAT))[lane];
    float ss = v.x*v.x + v.y*v.y + v.z*v.z + v.w*v.w;
    #pragma unroll
    for (int off = 1; off < 64; off <<= 1) ss += __shfl_xor(ss, off);
    float inv = 1.0f / fmaxf(sqrtf(ss), 1e-12f);
    float4 o; o.x = v.x*inv; o.y = v.y*inv; o.z = v.z*inv; o.w = v.w*inv;
    ushort4 b;
    b.x = f2bf(o.x); b.y = f2bf(o.y); b.z = f2bf(o.z); b.w = f2bf(o.w);
    ((ushort4*)(fb + row * FEAT))[lane] = b;
    // exchange normalized rows for the fp32 positive dot
    ((float4*)ex[wave])[lane] = o;
    __syncthreads();
    float4 p = ((float4*)ex[wave ^ 1])[lane];
    float d = o.x*p.x + o.y*p.y + o.z*p.z + o.w*p.w;
    #pragma unroll
    for (int off = 1; off < 64; off <<= 1) d += __shfl_xor(d, off);
    if (lane == 0) pos[row] = d;
}

// ---- Kernel 2: tiled f@f^T with fused fixed-max exp-sum ------------------
// grid (32, YSPLIT): x = row-block of 256 rows (8 waves x 32 rows),
//                    y = column split of CPB cols.
// s <= 1 (normalized rows), so accumulate exp((s-1)/T) = exp2(s*K - K).
__global__ __launch_bounds__(512)
void kmain(const unsigned short* __restrict__ fb, float* __restrict__ partial) {
    __shared__ unsigned short Bs[CT][LDS_STRIDE];   // 33,792 B
    const int t    = threadIdx.x;
    const int lane = t & 63;
    const int wave = t >> 6;          // 0..7
    const int quad = lane >> 4;       // 0..3
    const int l15  = lane & 15;
    const int rw    = blockIdx.x * 256 + wave * 32;
    const int cbase = blockIdx.y * CPB;
    const float Kc = 20.60992915555662f;              // log2(e)/0.07

    // A fragments: 32 rows x K=256 resident in registers (64 VGPRs)
    bf16x8 af[2][8];
    #pragma unroll
    for (int rf = 0; rf < 2; ++rf)
        #pragma unroll
        for (int ks = 0; ks < 8; ++ks) {
            int row = rw + rf * 16 + l15;
            int k   = ks * 32 + quad * 8;
            af[rf][ks] = *(const bf16x8*)(fb + row * FEAT + k);
        }

    float lsum[2][4] = {{0.f,0.f,0.f,0.f},{0.f,0.f,0.f,0.f}};

    for (int ct = 0; ct < CPB / CT; ++ct) {
        __syncthreads();
        const int c0 = cbase + ct * CT;
        #pragma unroll
        for (int i = 0; i < 4; ++i) {
            int idx = t + i * 512;
            int r = idx >> 5;
            int o = (idx & 31) * 8;
            *(uint4*)(&Bs[r][o]) = *(const uint4*)(fb + (c0 + r) * FEAT + o);
        }
        __syncthreads();

        #pragma unroll
        for (int g = 0; g < 4; ++g) {
            const int cg = c0 + g * 16;
            f32x4 acc0 = {0.f,0.f,0.f,0.f};
            f32x4 acc1 = {0.f,0.f,0.f,0.f};
            #pragma unroll
            for (int ks = 0; ks < 8; ++ks) {
                bf16x8 b = *(const bf16x8*)(&Bs[g * 16 + l15][ks * 32 + quad * 8]);
                acc0 = __builtin_amdgcn_mfma_f32_16x16x32_bf16(af[0][ks], b, acc0, 0, 0, 0);
                acc1 = __builtin_amdgcn_mfma_f32_16x16x32_bf16(af[1][ks], b, acc1, 0, 0, 0);
            }
            const bool dg = (cg < rw + 32) && (cg + 16 > rw);  // wave-uniform
            const int C = cg + l15;
            #pragma unroll
            for (int r = 0; r < 4; ++r) {
                float e0 = __builtin_amdgcn_exp2f(fmaf(acc0[r], Kc, -Kc));
                float e1 = __builtin_amdgcn_exp2f(fmaf(acc1[r], Kc, -Kc));
                if (dg) {
                    int R0 = rw + quad * 4 + r;
                    if (R0 == C)      e0 = 0.f;     // mask j == i
                    if (R0 + 16 == C) e1 = 0.f;
                }
                lsum[0][r] += e0;
                lsum[1][r] += e1;
            }
        }
    }

    #pragma unroll
    for (int rf = 0; rf < 2; ++rf)
        #pragma unroll
        for (int r = 0; r < 4; ++r) {
            float v = lsum[rf][r];
            v += __shfl_xor(v, 1);
            v += __shfl_xor(v, 2);
            v += __shfl_xor(v, 4);
            v += __shfl_xor(v, 8);
            lsum[rf][r] = v;
        }
    if (l15 == 0) {
        #pragma unroll
        for (int rf = 0; rf < 2; ++rf)
            #pragma unroll
            for (int r = 0; r < 4; ++r) {
                int row = rw + rf * 16 + quad * 4 + r;
                partial[blockIdx.y * N_ROWS + row] = lsum[rf][r];
            }
    }
}

// ---- Kernel 3: per-row loss + block tree-reduce (no same-address atomics)
__global__ void kreduce(const float* __restrict__ partial,
                        const float* __restrict__ pos,
                        float* __restrict__ bsum) {
    __shared__ float red[4];
    int row  = blockIdx.x * 256 + threadIdx.x;
    int wave = threadIdx.x >> 6;
    int lane = threadIdx.x & 63;
    float L = 0.f;
    #pragma unroll
    for (int p = 0; p < YSPLIT; ++p) L += partial[p * N_ROWS + row];
    const float invT = 14.285714285714286f;
    // loss_i = (1 - pos_i)/T + ln2 * log2(L)   (v_log_f32 is log2)
    float loss = invT * (1.0f - pos[row])
               + 0.6931471805599453f * __builtin_amdgcn_logf(L);
    #pragma unroll
    for (int off = 1; off < 64; off <<= 1) loss += __shfl_xor(loss, off);
    if (lane == 0) red[wave] = loss;
    __syncthreads();
    if (threadIdx.x == 0)
        bsum[blockIdx.x] = red[0] + red[1] + red[2] + red[3];
}

// ---- Kernel 4: final 32 -> 1 ---------------------------------------------
__global__ void kfinal(const float* __restrict__ bsum, float* __restrict__ out) {
    int lane = threadIdx.x;
    float v = (lane < 32) ? bsum[lane] : 0.f;
    #pragma unroll
    for (int off = 1; off < 32; off <<= 1) v += __shfl_xor(v, off);
    if (lane == 0) out[0] = v * (1.0f / 8192.0f);
}

extern "C" void kernel_launch(void* const* d_in, const int* in_sizes, int n_in,
                              void* d_out, int out_size, void* d_ws, size_t ws_size,
                              hipStream_t stream) {
    const float* feat = (const float*)d_in[0];
    float* out = (float*)d_out;
    char* ws = (char*)d_ws;
    unsigned short* fb      = (unsigned short*)ws;                    // 4 MB bf16
    float*          partial = (float*)(ws + (4u << 20));              // 512 KB
    float*          pos     = (float*)(ws + (4u << 20) + (1u << 19)); // 32 KB
    float*          bsum    = (float*)(ws + (4u << 20) + (1u << 19) + (1u << 15));

    knorm<<<N_ROWS / 4, 256, 0, stream>>>(feat, fb, pos);
    kmain<<<dim3(32, YSPLIT), 512, 0, stream>>>(fb, partial);
    kreduce<<<N_ROWS / 256, 256, 0, stream>>>(partial, pos, bsum);
    kfinal<<<1, 64, 0, stream>>>(bsum, out);
}